// Round 18
// baseline (111.238 us; speedup 1.0000x reference)
//
#include <hip/hip_runtime.h>
#include <cstdint>
#include <cstddef>

typedef unsigned short u16;
typedef uint32_t u32;
typedef __bf16 bf16x8 __attribute__((ext_vector_type(8)));
typedef float  f32x4  __attribute__((ext_vector_type(4)));
typedef u16    u16x4  __attribute__((ext_vector_type(4)));
typedef u32    u32x4  __attribute__((ext_vector_type(4)));

#define DEV static __device__ __forceinline__
#define MFMA16(a, b, c) __builtin_amdgcn_mfma_f32_16x16x32_bf16(a, b, c, 0, 0, 0)

DEV u16 f2bf(float x) {
  unsigned u = __float_as_uint(x);
  u += 0x7fffu + ((u >> 16) & 1u);
  return (u16)(u >> 16);
}

DEV u32 cvt_pk_bf16(float lo, float hi) {  // [15:0]=bf16(lo), [31:16]=bf16(hi), RNE
  u32 r;
  asm("v_cvt_pk_bf16_f32 %0, %1, %2" : "=v"(r) : "v"(lo), "v"(hi));
  return r;
}

DEV void gload_lds16(const void* g, void* l) {
  __builtin_amdgcn_global_load_lds(
      (__attribute__((address_space(1))) void*)(void*)g,
      (__attribute__((address_space(3))) void*)l, 16, 0, 0);
}

// ---------------- prep: 4 weight transposes + q fp32->bf16, ONE dispatch ----------------
// z=0: Wq^T, z=1: Wo^T, z=2: Wk^T, z=3: Wv^T, z=4: q convert (1024 blocks x 4 f32x4/thr)
__global__ void k_prep(const float* __restrict__ Wq, u16* __restrict__ WqT,
                       const float* __restrict__ Wo, u16* __restrict__ WoT,
                       const float* __restrict__ Wk, u16* __restrict__ WkT,
                       const float* __restrict__ Wv, u16* __restrict__ WvT,
                       const float* __restrict__ q, u16* __restrict__ qbf) {
  __shared__ float tile[32][33];
  const int z = blockIdx.z;
  if (z == 4) {  // convert q: 4096*1024 f32 = 1,048,576 f32x4 over 1024 blocks
    const int bid = blockIdx.y * 32 + blockIdx.x;
    const int tid = threadIdx.y * 32 + threadIdx.x;
    const f32x4* src = (const f32x4*)q;
    u16x4* dst = (u16x4*)qbf;
#pragma unroll
    for (int i = 0; i < 4; ++i) {
      const int idx = bid * 1024 + i * 256 + tid;
      f32x4 f = src[idx];
      u16x4 o;
      o[0] = f2bf(f[0]); o[1] = f2bf(f[1]); o[2] = f2bf(f[2]); o[3] = f2bf(f[3]);
      dst[idx] = o;
    }
    return;
  }
  const int C = z < 2 ? 1024 : 64;
  constexpr int R = 1024;
  if (blockIdx.x * 32 >= C) return;
  const float* in = z == 0 ? Wq : z == 1 ? Wo : z == 2 ? Wk : Wv;
  u16* out = z == 0 ? WqT : z == 1 ? WoT : z == 2 ? WkT : WvT;
  int bx = blockIdx.x * 32, by = blockIdx.y * 32;
  int tx = threadIdx.x, ty = threadIdx.y;
#pragma unroll
  for (int j = 0; j < 4; ++j)
    tile[ty + j * 8][tx] = in[(size_t)(by + ty + j * 8) * C + bx + tx];
  __syncthreads();
#pragma unroll
  for (int j = 0; j < 4; ++j)
    out[(size_t)(bx + ty + j * 8) * R + by + tx] = f2bf(tile[tx][ty + j * 8]);
}

// ---------------- 128x128 tile NT GEMM v3: ring-2 pipelined, 8 waves, XCD swizzle ----------------
// (bf16-A variant used for the O-projection.)
template <bool OUT_BF16, bool A_FP32>
__global__ __launch_bounds__(512) void k_gemm128(const void* __restrict__ Ap, const u16* __restrict__ Bt,
                                                 const float* __restrict__ bias, void* __restrict__ Cout,
                                                 int M, int N, int K, float scale) {
  __shared__ u16 As[2][128 * 32];
  __shared__ u16 Bs[2][128 * 32];
  const int tid = threadIdx.x, lane = tid & 63, wid = tid >> 6;  // wid 0..7
  const int s = blockIdx.x;
  const int xr = s & 7, t = s >> 3;
  const int bx = t & 7;
  const int by = (t >> 3) * 8 + xr;   // by % 8 == XCD id
  const int brow = by * 128, bcol = bx * 128;
  const int wr = (wid >> 2) * 64, wc = (wid & 3) * 32;

  const int e0 = wid * 512 + lane * 8;
  const u16* b0 = Bt + (size_t)(bcol + (e0 >> 5)) * K + (e0 & 31);
  const u16* a0bf = A_FP32 ? nullptr : (const u16*)Ap + (size_t)(brow + (e0 >> 5)) * K + (e0 & 31);
  const float* a0f = A_FP32 ? (const float*)Ap + (size_t)(brow + (tid >> 2)) * K + (tid & 3) * 8 : nullptr;

  f32x4 ra0, ra1;
  auto LOADA = [&](int k0) {
    ra0 = *(const f32x4*)(a0f + k0);
    ra1 = *(const f32x4*)(a0f + k0 + 4);
  };
  auto WRITEA = [&](int buf) {
    u32x4 w;
    w[0] = cvt_pk_bf16(ra0[0], ra0[1]);
    w[1] = cvt_pk_bf16(ra0[2], ra0[3]);
    w[2] = cvt_pk_bf16(ra1[0], ra1[1]);
    w[3] = cvt_pk_bf16(ra1[2], ra1[3]);
    *(u32x4*)&As[buf][tid * 8] = w;
  };

  f32x4 acc[4][2] = {};
  const int NK = K / 32;
  if constexpr (A_FP32) {
    LOADA(0);
    gload_lds16(b0, &Bs[0][wid * 512]);
    WRITEA(0);
    LOADA(32);
    asm volatile("s_waitcnt lgkmcnt(0)" ::: "memory");
  } else {
    gload_lds16(a0bf, &As[0][wid * 512]);
    gload_lds16(b0, &Bs[0][wid * 512]);
  }
#pragma unroll 1
  for (int ks = 0; ks < NK; ++ks) {
    if (ks + 1 < NK) {
      if constexpr (A_FP32) {
        gload_lds16(b0 + (ks + 1) * 32, &Bs[(ks + 1) & 1][wid * 512]);
        asm volatile("s_waitcnt vmcnt(3)\n\ts_barrier" ::: "memory");
      } else {
        gload_lds16(a0bf + (ks + 1) * 32, &As[(ks + 1) & 1][wid * 512]);
        gload_lds16(b0 + (ks + 1) * 32, &Bs[(ks + 1) & 1][wid * 512]);
        asm volatile("s_waitcnt vmcnt(2)\n\ts_barrier" ::: "memory");
      }
    } else {
      asm volatile("s_waitcnt vmcnt(0)\n\ts_barrier" ::: "memory");
    }
    __builtin_amdgcn_sched_barrier(0);

    const u16* Ab = &As[ks & 1][0];
    const u16* Bb = &Bs[ks & 1][0];
    const int lr = lane & 15, lk = (lane >> 4) * 8;
    bf16x8 af[4], bfr[2];
#pragma unroll
    for (int m = 0; m < 4; ++m) af[m] = *(const bf16x8*)&Ab[(wr + m * 16 + lr) * 32 + lk];
#pragma unroll
    for (int n = 0; n < 2; ++n) bfr[n] = *(const bf16x8*)&Bb[(wc + n * 16 + lr) * 32 + lk];
    __builtin_amdgcn_s_setprio(1);
#pragma unroll
    for (int m = 0; m < 4; ++m)
#pragma unroll
      for (int n = 0; n < 2; ++n) acc[m][n] = MFMA16(af[m], bfr[n], acc[m][n]);
    __builtin_amdgcn_s_setprio(0);

    if constexpr (A_FP32) {
      if (ks + 1 < NK) {
        WRITEA((ks + 1) & 1);
        if (ks + 2 < NK) LOADA((ks + 2) * 32);
      }
      asm volatile("s_waitcnt lgkmcnt(0)\n\ts_barrier" ::: "memory");
    } else {
      asm volatile("s_barrier" ::: "memory");
    }
  }

  const int lr = lane & 15, lg = lane >> 4;
#pragma unroll
  for (int m = 0; m < 4; ++m)
#pragma unroll
    for (int n = 0; n < 2; ++n) {
      const int col = bcol + wc + n * 16 + lr;
      const float bv = bias ? bias[col] : 0.f;
#pragma unroll
      for (int r = 0; r < 4; ++r) {
        const int row = brow + wr + m * 16 + lg * 4 + r;
        float val = (acc[m][n][r] + bv) * scale;
        if constexpr (OUT_BF16) ((u16*)Cout)[(size_t)row * N + col] = f2bf(val);
        else ((float*)Cout)[(size_t)row * N + col] = val;
      }
    }
}

// ---------------- fused K+V projections v2: fp32 A, ring-2 pipelined (r14 verified) ----------------
__global__ __launch_bounds__(256) void k_gemm64(const float* __restrict__ A0, const float* __restrict__ A1,
                                                const u16* __restrict__ Bt0, const u16* __restrict__ Bt1,
                                                const float* __restrict__ bias0, const float* __restrict__ bias1,
                                                u16* __restrict__ C0, u16* __restrict__ C1, int K) {
  __shared__ u16 As[2][64 * 32];
  __shared__ u16 Bs[2][64 * 32];
  const int sel = blockIdx.y;
  const float* Af = sel ? A1 : A0;
  const u16* Bt = sel ? Bt1 : Bt0;
  const float* bias = sel ? bias1 : bias0;
  const int tid = threadIdx.x, lane = tid & 63, wid = tid >> 6;  // 4 waves
  const int brow = blockIdx.x * 64;
  const int e0 = wid * 512 + lane * 8;
  const u16* b0 = Bt + (size_t)(e0 >> 5) * K + (e0 & 31);
  const float* a0f = Af + (size_t)(brow + (tid >> 2)) * K + (tid & 3) * 8;

  f32x4 ra0, ra1;
  auto LOADA = [&](int k0) {
    ra0 = *(const f32x4*)(a0f + k0);
    ra1 = *(const f32x4*)(a0f + k0 + 4);
  };
  auto WRITEA = [&](int buf) {
    u32x4 w;
    w[0] = cvt_pk_bf16(ra0[0], ra0[1]);
    w[1] = cvt_pk_bf16(ra0[2], ra0[3]);
    w[2] = cvt_pk_bf16(ra1[0], ra1[1]);
    w[3] = cvt_pk_bf16(ra1[2], ra1[3]);
    *(u32x4*)&As[buf][tid * 8] = w;
  };

  f32x4 acc[4] = {};
  const int NK = K / 32;
  LOADA(0);
  gload_lds16(b0, &Bs[0][wid * 512]);
  WRITEA(0);
  LOADA(32);
  asm volatile("s_waitcnt lgkmcnt(0)" ::: "memory");
#pragma unroll 1
  for (int ks = 0; ks < NK; ++ks) {
    if (ks + 1 < NK) {
      gload_lds16(b0 + (ks + 1) * 32, &Bs[(ks + 1) & 1][wid * 512]);
      asm volatile("s_waitcnt vmcnt(3)\n\ts_barrier" ::: "memory");
    } else {
      asm volatile("s_waitcnt vmcnt(0)\n\ts_barrier" ::: "memory");
    }
    __builtin_amdgcn_sched_barrier(0);

    const u16* Ab = &As[ks & 1][0];
    const u16* Bb = &Bs[ks & 1][0];
    const int lr = lane & 15, lk = (lane >> 4) * 8;
    bf16x8 af = *(const bf16x8*)&Ab[(wid * 16 + lr) * 32 + lk];
    __builtin_amdgcn_s_setprio(1);
#pragma unroll
    for (int n = 0; n < 4; ++n) {
      bf16x8 bfr = *(const bf16x8*)&Bb[(n * 16 + lr) * 32 + lk];
      acc[n] = MFMA16(af, bfr, acc[n]);
    }
    __builtin_amdgcn_s_setprio(0);

    if (ks + 1 < NK) {
      WRITEA((ks + 1) & 1);
      if (ks + 2 < NK) LOADA((ks + 2) * 32);
    }
    asm volatile("s_waitcnt lgkmcnt(0)\n\ts_barrier" ::: "memory");
  }

  const int lr = lane & 15, lg = lane >> 4;
#pragma unroll
  for (int n = 0; n < 4; ++n) {
    const int col = n * 16 + lr;
    const float bv = bias[col];
#pragma unroll
    for (int r = 0; r < 4; ++r) {
      const int row = brow + wid * 16 + lg * 4 + r;
      const float val = acc[n][r] + bv;
      if (sel)
        C1[((size_t)(row >> 11) * 64 + col) * 2048 + (row & 2047)] = f2bf(val);
      else
        C0[(size_t)row * 64 + col] = f2bf(val);
    }
  }
}

// ---------------- flash attention (MQA) v12: bf16 gload Q-phase + r12 attn core ----------------
// Grid (S/128, H, B): blocks sharing q-tile x have ids x+16h -> all on XCD x%8
// (q-tile L2-resident, fetched once). Q-phase now pure gload_lds (q pre-converted
// to bf16 by k_prep): per k-step 3 gloads (A rows via 2, B rows via 1), all with
// PRE-swizzled global source chunk (c' = c ^ (row&7), rule #21) and linear LDS
// dest -> swizzled tile; fragment reads XOR the same key. No in-loop ds_writes
// -> bottom barrier is plain (r13-proven); top wait vmcnt(3) = next tile's 3
// loads in flight, current tile forced complete. Attn core = r12 (50.4us).
__global__ __launch_bounds__(512) void k_attn(const u16* __restrict__ qbf, const u16* __restrict__ WqT,
                                              const float* __restrict__ bq,
                                              const u16* __restrict__ Kh, const u16* __restrict__ VhT,
                                              u16* __restrict__ Out) {
  constexpr int S = 2048, D = 1024, NT = 32, K = 1024;
  __shared__ __align__(16) char smem[49152];
  const int tid = threadIdx.x, lane = tid & 63, wid = tid >> 6;
  const int lr = lane & 15, lg = lane >> 4;
  const int q0 = blockIdx.x * 128;          // q fastest: same-q blocks land on one XCD
  const int h = blockIdx.y;
  const int b = blockIdx.z;

  const int r8 = lane >> 3, ssl = (lane & 7) ^ r8;  // pre-swizzled source chunk (row&7 == r8)

  // ---- Q-projection phase: AsQ [2][128][64] @0 (32KB), BsQ [2][64][64] @32K (16KB) ----
  u16* AsQ = (u16*)smem;
  u16* BsQ = (u16*)(smem + 32768);
  u16* Qlds = (u16*)(smem + 32768);         // [128][64] linear (post-loop, = Ps region)

  {
    const u16* qa = qbf + (size_t)(b * S + q0 + wid * 16 + r8) * K + ssl * 8;
    const u16* qb = WqT + (size_t)(h * 64 + wid * 8 + r8) * K + ssl * 8;

    auto STAGEQ = [&](int buf, int ks) {
      gload_lds16(qa + ks * 64, &AsQ[buf * 8192 + (wid * 16) * 64]);
      gload_lds16(qa + ks * 64 + (size_t)8 * K, &AsQ[buf * 8192 + (wid * 16 + 8) * 64]);
      gload_lds16(qb + ks * 64, &BsQ[buf * 4096 + (wid * 8) * 64]);
    };

    f32x4 accq[4] = {};
    STAGEQ(0, 0);
#pragma unroll 1
    for (int ks = 0; ks < 16; ++ks) {
      if (ks + 1 < 16) {
        STAGEQ((ks + 1) & 1, ks + 1);
        asm volatile("s_waitcnt vmcnt(3)\n\ts_barrier" ::: "memory");
      } else {
        asm volatile("s_waitcnt vmcnt(0)\n\ts_barrier" ::: "memory");
      }
      __builtin_amdgcn_sched_barrier(0);

      const char* Ab = (const char*)(AsQ + (ks & 1) * 8192);
      const char* Bb = (const char*)(BsQ + (ks & 1) * 4096);
      bf16x8 af[2];
#pragma unroll
      for (int kk = 0; kk < 2; ++kk) {
        const int row = wid * 16 + lr;
        af[kk] = *(const bf16x8*)(Ab + row * 128 + (((kk * 4 + lg) ^ (row & 7)) << 4));
      }
      __builtin_amdgcn_s_setprio(1);
#pragma unroll
      for (int kk = 0; kk < 2; ++kk)
#pragma unroll
        for (int n = 0; n < 4; ++n) {
          const int row = n * 16 + lr;
          bf16x8 bfr = *(const bf16x8*)(Bb + row * 128 + (((kk * 4 + lg) ^ (row & 7)) << 4));
          accq[n] = MFMA16(af[kk], bfr, accq[n]);
        }
      __builtin_amdgcn_s_setprio(0);
      asm volatile("s_barrier" ::: "memory");  // ring-2: reads of buf ks&1 done before overwrite
    }
    // all waves' final frag reads complete before Qlds (BsQ region) overwrite
    asm volatile("s_waitcnt lgkmcnt(0)\n\ts_barrier" ::: "memory");
    // Q-tile -> Qlds (linear [128][64], own wave rows), scale + bias folded
    const float qscale = 0.125f * 1.44269504089f;
#pragma unroll
    for (int n = 0; n < 4; ++n) {
      const float bv = bq[h * 64 + n * 16 + lr];
#pragma unroll
      for (int r = 0; r < 4; ++r)
        Qlds[(wid * 16 + lg * 4 + r) * 64 + n * 16 + lr] = f2bf((accq[n][r] + bv) * qscale);
    }
    asm volatile("s_waitcnt lgkmcnt(0)\n\ts_barrier" ::: "memory");
  }

  // ---- attention (r12 core) ----
  u16* Ks0 = (u16*)smem;                    // [2][64*64] = 16KB
  u16* Vs0 = (u16*)(smem + 16384);          // [2][64*64] = 16KB
  u16* Pw = Qlds + wid * (16 * 64);         // own slab of Ps region

  bf16x8 qf[2];
#pragma unroll
  for (int kk = 0; kk < 2; ++kk)
    qf[kk] = *(const bf16x8*)&Qlds[(wid * 16 + lr) * 64 + kk * 32 + lg * 8];

  const u16* ksrc = Kh + (size_t)(b * S + wid * 8 + r8) * 64 + ssl * 8;
  const u16* vsrc = VhT + (size_t)(b * 64 + wid * 8 + r8) * S + ssl * 8;

  float lsum = 0.f;
  f32x4 o[4] = {};
  const int pswz = (lr & 7) << 3;

  auto STAGE = [&](int buf, int t) {
    gload_lds16(ksrc + (size_t)(t * 64) * 64, &Ks0[buf * (64 * 64) + (wid * 8) * 64]);
    gload_lds16(vsrc + t * 64, &Vs0[buf * (64 * 64) + (wid * 8) * 64]);
  };

  STAGE(0, 0);
#pragma unroll 1
  for (int t = 0; t < NT; ++t) {
    if (t + 1 < NT) {
      STAGE((t + 1) & 1, t + 1);
      asm volatile("s_waitcnt vmcnt(2)\n\ts_barrier" ::: "memory");
    } else {
      asm volatile("s_waitcnt vmcnt(0)\n\ts_barrier" ::: "memory");
    }
    __builtin_amdgcn_sched_barrier(0);

    const u16* Kb = &Ks0[(t & 1) * (64 * 64)];
    const u16* Vb = &Vs0[(t & 1) * (64 * 64)];

    // QK^T swapped: z[ct][r] = S2[q = lr][kv = ct*16 + lg*4 + r]   (log2 domain)
    f32x4 z[4] = {};
    __builtin_amdgcn_s_setprio(1);
#pragma unroll
    for (int kk = 0; kk < 2; ++kk)
#pragma unroll
      for (int ct = 0; ct < 4; ++ct) {
        const int row = ct * 16 + lr;
        bf16x8 kf = *(const bf16x8*)&Kb[row * 64 + (((kk * 4 + lg) ^ (row & 7)) << 3)];
        z[ct] = MFMA16(kf, qf[kk], z[ct]);
      }
    __builtin_amdgcn_s_setprio(0);

    // P = exp2(z) (static max), pack to bf16, per-wave LDS (swizzled)
    float s = 0.f;
#pragma unroll
    for (int ct = 0; ct < 4; ++ct) {
      const float p0 = __builtin_amdgcn_exp2f(z[ct][0]);
      const float p1 = __builtin_amdgcn_exp2f(z[ct][1]);
      const float p2 = __builtin_amdgcn_exp2f(z[ct][2]);
      const float p3 = __builtin_amdgcn_exp2f(z[ct][3]);
      s += (p0 + p1) + (p2 + p3);
      uint2 pk;
      pk.x = cvt_pk_bf16(p0, p1);
      pk.y = cvt_pk_bf16(p2, p3);
      *(uint2*)&Pw[lr * 64 + ((ct * 16 + lg * 4) ^ pswz)] = pk;
    }
    lsum += s;

    // PV: o[nt][r] += P[q][kv] * V^T[d][kv],  q = lg*4+r, d = nt*16+lr
#pragma unroll
    for (int kk = 0; kk < 2; ++kk) {
      bf16x8 pa = *(const bf16x8*)&Pw[lr * 64 + ((kk * 32 + lg * 8) ^ pswz)];
      __builtin_amdgcn_s_setprio(1);
#pragma unroll
      for (int nt = 0; nt < 4; ++nt) {
        const int row = nt * 16 + lr;
        bf16x8 vf = *(const bf16x8*)&Vb[row * 64 + (((kk * 4 + lg) ^ (row & 7)) << 3)];
        o[nt] = MFMA16(pa, vf, o[nt]);
      }
      __builtin_amdgcn_s_setprio(0);
    }
    asm volatile("s_barrier" ::: "memory");
  }

  // epilogue: reduce per-lane l partials, divide, store
  lsum += __shfl_xor(lsum, 16);
  lsum += __shfl_xor(lsum, 32);
  const float linv = 1.f / lsum;
#pragma unroll
  for (int r = 0; r < 4; ++r) {
    const float li = __shfl(linv, (lane & 48) | (lg * 4 + r));
    const size_t row = (size_t)(b * S + q0 + wid * 16 + lg * 4 + r);
#pragma unroll
    for (int nt = 0; nt < 4; ++nt)
      Out[row * D + h * 64 + nt * 16 + lr] = f2bf(o[nt][r] * li);
  }
}

// ---------------- launcher ----------------
extern "C" void kernel_launch(void* const* d_in, const int* in_sizes, int n_in,
                              void* d_out, int out_size, void* d_ws, size_t ws_size,
                              hipStream_t stream) {
  const float* q  = (const float*)d_in[0];
  const float* k  = (const float*)d_in[1];
  const float* v  = (const float*)d_in[2];
  const float* Wq = (const float*)d_in[3];
  const float* bq = (const float*)d_in[4];
  const float* Wk = (const float*)d_in[5];
  const float* bk = (const float*)d_in[6];
  const float* Wv = (const float*)d_in[7];
  const float* bv = (const float*)d_in[8];
  const float* Wo = (const float*)d_in[9];
  const float* bo = (const float*)d_in[10];
  float* out = (float*)d_out;

  constexpr int B = 2, S = 2048, D = 1024, H = 16, HDc = 64;
  constexpr int M = B * S;  // 4096

  char* ws = (char*)d_ws;
  size_t off = 0;
  auto alloc = [&](size_t bytes) { char* p = ws + off; off += bytes; return p; };
  u16* WqT  = (u16*)alloc((size_t)D * D * 2);
  u16* WkvT = (u16*)alloc((size_t)2 * HDc * D * 2);
  u16* WoT  = (u16*)alloc((size_t)D * D * 2);
  u16* Kh   = (u16*)alloc((size_t)M * HDc * 2);
  u16* VhT  = (u16*)alloc((size_t)M * HDc * 2);
  u16* AO   = (u16*)alloc((size_t)M * D * 2);
  u16* q_bf = (u16*)alloc((size_t)M * D * 2);
  u16* WkT = WkvT;
  u16* WvT = WkvT + (size_t)HDc * D;

  // weight transposes + q convert, one dispatch
  k_prep<<<dim3(32, 32, 5), dim3(32, 8), 0, stream>>>(Wq, WqT, Wo, WoT, Wk, WkT, Wv, WvT, q, q_bf);
  // fused K + V projections — fp32 A, distinct inputs
  k_gemm64<<<dim3(M / 64, 2), 256, 0, stream>>>(k, v, WkT, WvT, bk, bv, Kh, VhT, D);
  // attention with fused Q-projection (bf16 gload staging); grid (S/128, H, B)
  k_attn<<<dim3(S / 128, H, B), 512, 0, stream>>>(q_bf, WqT, bq, Kh, VhT, AO);
  // output projection (bf16 A via gload_lds, fp32 out + bias)
  k_gemm128<false, false><<<dim3((M / 128) * (D / 128)), 512, 0, stream>>>(AO, WoT, bo, out, M, D, D, 1.0f);
}

// Round 19
// 108.483 us; speedup vs baseline: 1.0254x; 1.0254x over previous
//
#include <hip/hip_runtime.h>
#include <cstdint>
#include <cstddef>

typedef unsigned short u16;
typedef uint32_t u32;
typedef __bf16 bf16x8 __attribute__((ext_vector_type(8)));
typedef float  f32x4  __attribute__((ext_vector_type(4)));
typedef u16    u16x4  __attribute__((ext_vector_type(4)));
typedef u32    u32x4  __attribute__((ext_vector_type(4)));

#define DEV static __device__ __forceinline__
#define MFMA16(a, b, c) __builtin_amdgcn_mfma_f32_16x16x32_bf16(a, b, c, 0, 0, 0)

DEV u16 f2bf(float x) {
  unsigned u = __float_as_uint(x);
  u += 0x7fffu + ((u >> 16) & 1u);
  return (u16)(u >> 16);
}

DEV u32 cvt_pk_bf16(float lo, float hi) {  // [15:0]=bf16(lo), [31:16]=bf16(hi), RNE
  u32 r;
  asm("v_cvt_pk_bf16_f32 %0, %1, %2" : "=v"(r) : "v"(lo), "v"(hi));
  return r;
}

DEV void gload_lds16(const void* g, void* l) {
  __builtin_amdgcn_global_load_lds(
      (__attribute__((address_space(1))) void*)(void*)g,
      (__attribute__((address_space(3))) void*)l, 16, 0, 0);
}

// ---------------- all 4 weight transposes in ONE dispatch (r17 version) ----------------
__global__ void k_transpose4(const float* __restrict__ Wq, u16* __restrict__ WqT,
                             const float* __restrict__ Wo, u16* __restrict__ WoT,
                             const float* __restrict__ Wk, u16* __restrict__ WkT,
                             const float* __restrict__ Wv, u16* __restrict__ WvT) {
  __shared__ float tile[32][33];
  const int z = blockIdx.z;
  const int C = z < 2 ? 1024 : 64;
  constexpr int R = 1024;
  if (blockIdx.x * 32 >= C) return;
  const float* in = z == 0 ? Wq : z == 1 ? Wo : z == 2 ? Wk : Wv;
  u16* out = z == 0 ? WqT : z == 1 ? WoT : z == 2 ? WkT : WvT;
  int bx = blockIdx.x * 32, by = blockIdx.y * 32;
  int tx = threadIdx.x, ty = threadIdx.y;
#pragma unroll
  for (int j = 0; j < 4; ++j)
    tile[ty + j * 8][tx] = in[(size_t)(by + ty + j * 8) * C + bx + tx];
  __syncthreads();
#pragma unroll
  for (int j = 0; j < 4; ++j)
    out[(size_t)(bx + ty + j * 8) * R + by + tx] = f2bf(tile[tx][ty + j * 8]);
}

// ---------------- 128x128 tile NT GEMM v3: ring-2 pipelined, 8 waves, XCD swizzle ----------------
// (bf16-A variant used for the O-projection.)
template <bool OUT_BF16, bool A_FP32>
__global__ __launch_bounds__(512) void k_gemm128(const void* __restrict__ Ap, const u16* __restrict__ Bt,
                                                 const float* __restrict__ bias, void* __restrict__ Cout,
                                                 int M, int N, int K, float scale) {
  __shared__ u16 As[2][128 * 32];
  __shared__ u16 Bs[2][128 * 32];
  const int tid = threadIdx.x, lane = tid & 63, wid = tid >> 6;  // wid 0..7
  const int s = blockIdx.x;
  const int xr = s & 7, t = s >> 3;
  const int bx = t & 7;
  const int by = (t >> 3) * 8 + xr;   // by % 8 == XCD id
  const int brow = by * 128, bcol = bx * 128;
  const int wr = (wid >> 2) * 64, wc = (wid & 3) * 32;

  const int e0 = wid * 512 + lane * 8;
  const u16* b0 = Bt + (size_t)(bcol + (e0 >> 5)) * K + (e0 & 31);
  const u16* a0bf = A_FP32 ? nullptr : (const u16*)Ap + (size_t)(brow + (e0 >> 5)) * K + (e0 & 31);
  const float* a0f = A_FP32 ? (const float*)Ap + (size_t)(brow + (tid >> 2)) * K + (tid & 3) * 8 : nullptr;

  f32x4 ra0, ra1;
  auto LOADA = [&](int k0) {
    ra0 = *(const f32x4*)(a0f + k0);
    ra1 = *(const f32x4*)(a0f + k0 + 4);
  };
  auto WRITEA = [&](int buf) {
    u32x4 w;
    w[0] = cvt_pk_bf16(ra0[0], ra0[1]);
    w[1] = cvt_pk_bf16(ra0[2], ra0[3]);
    w[2] = cvt_pk_bf16(ra1[0], ra1[1]);
    w[3] = cvt_pk_bf16(ra1[2], ra1[3]);
    *(u32x4*)&As[buf][tid * 8] = w;
  };

  f32x4 acc[4][2] = {};
  const int NK = K / 32;
  if constexpr (A_FP32) {
    LOADA(0);
    gload_lds16(b0, &Bs[0][wid * 512]);
    WRITEA(0);
    LOADA(32);
    asm volatile("s_waitcnt lgkmcnt(0)" ::: "memory");
  } else {
    gload_lds16(a0bf, &As[0][wid * 512]);
    gload_lds16(b0, &Bs[0][wid * 512]);
  }
#pragma unroll 1
  for (int ks = 0; ks < NK; ++ks) {
    if (ks + 1 < NK) {
      if constexpr (A_FP32) {
        gload_lds16(b0 + (ks + 1) * 32, &Bs[(ks + 1) & 1][wid * 512]);
        asm volatile("s_waitcnt vmcnt(3)\n\ts_barrier" ::: "memory");
      } else {
        gload_lds16(a0bf + (ks + 1) * 32, &As[(ks + 1) & 1][wid * 512]);
        gload_lds16(b0 + (ks + 1) * 32, &Bs[(ks + 1) & 1][wid * 512]);
        asm volatile("s_waitcnt vmcnt(2)\n\ts_barrier" ::: "memory");
      }
    } else {
      asm volatile("s_waitcnt vmcnt(0)\n\ts_barrier" ::: "memory");
    }
    __builtin_amdgcn_sched_barrier(0);

    const u16* Ab = &As[ks & 1][0];
    const u16* Bb = &Bs[ks & 1][0];
    const int lr = lane & 15, lk = (lane >> 4) * 8;
    bf16x8 af[4], bfr[2];
#pragma unroll
    for (int m = 0; m < 4; ++m) af[m] = *(const bf16x8*)&Ab[(wr + m * 16 + lr) * 32 + lk];
#pragma unroll
    for (int n = 0; n < 2; ++n) bfr[n] = *(const bf16x8*)&Bb[(wc + n * 16 + lr) * 32 + lk];
    __builtin_amdgcn_s_setprio(1);
#pragma unroll
    for (int m = 0; m < 4; ++m)
#pragma unroll
      for (int n = 0; n < 2; ++n) acc[m][n] = MFMA16(af[m], bfr[n], acc[m][n]);
    __builtin_amdgcn_s_setprio(0);

    if constexpr (A_FP32) {
      if (ks + 1 < NK) {
        WRITEA((ks + 1) & 1);
        if (ks + 2 < NK) LOADA((ks + 2) * 32);
      }
      asm volatile("s_waitcnt lgkmcnt(0)\n\ts_barrier" ::: "memory");
    } else {
      asm volatile("s_barrier" ::: "memory");
    }
  }

  const int lr = lane & 15, lg = lane >> 4;
#pragma unroll
  for (int m = 0; m < 4; ++m)
#pragma unroll
    for (int n = 0; n < 2; ++n) {
      const int col = bcol + wc + n * 16 + lr;
      const float bv = bias ? bias[col] : 0.f;
#pragma unroll
      for (int r = 0; r < 4; ++r) {
        const int row = brow + wr + m * 16 + lg * 4 + r;
        float val = (acc[m][n][r] + bv) * scale;
        if constexpr (OUT_BF16) ((u16*)Cout)[(size_t)row * N + col] = f2bf(val);
        else ((float*)Cout)[(size_t)row * N + col] = val;
      }
    }
}

// ---------------- fused K+V projections + q-convert rideshare ----------------
// y==0: Kh = k @ WkT^T + bk (row-major).  y==1: VhT (transposed V, from v @ WvT^T + bv).
// y>=2: q fp32->bf16 convert, 256 blocks riding the idle CUs (this dispatch has
// only 128 GEMM blocks = 0.5/CU; the convert fills the other half and finishes
// before k_attn, which is the only consumer of q_bf).
__global__ __launch_bounds__(256) void k_gemm64(const float* __restrict__ A0, const float* __restrict__ A1,
                                                const u16* __restrict__ Bt0, const u16* __restrict__ Bt1,
                                                const float* __restrict__ bias0, const float* __restrict__ bias1,
                                                u16* __restrict__ C0, u16* __restrict__ C1, int K,
                                                const float* __restrict__ qsrc, u16* __restrict__ qbf) {
  const int sel = blockIdx.y;
  if (sel >= 2) {  // q convert: slice (sel-2) of 4, 64 blocks each; 4096 f32x4/block
    const f32x4* src = (const f32x4*)qsrc;
    u16x4* dst = (u16x4*)qbf;
    const int base = ((sel - 2) * 64 + blockIdx.x) * 4096 + threadIdx.x;
#pragma unroll 4
    for (int i = 0; i < 16; ++i) {
      f32x4 f = src[base + i * 256];
      u16x4 o;
      o[0] = f2bf(f[0]); o[1] = f2bf(f[1]); o[2] = f2bf(f[2]); o[3] = f2bf(f[3]);
      dst[base + i * 256] = o;
    }
    return;
  }
  __shared__ u16 As[2][64 * 32];
  __shared__ u16 Bs[2][64 * 32];
  const float* Af = sel ? A1 : A0;
  const u16* Bt = sel ? Bt1 : Bt0;
  const float* bias = sel ? bias1 : bias0;
  const int tid = threadIdx.x, lane = tid & 63, wid = tid >> 6;  // 4 waves
  const int brow = blockIdx.x * 64;
  const int e0 = wid * 512 + lane * 8;
  const u16* b0 = Bt + (size_t)(e0 >> 5) * K + (e0 & 31);
  const float* a0f = Af + (size_t)(brow + (tid >> 2)) * K + (tid & 3) * 8;

  f32x4 ra0, ra1;
  auto LOADA = [&](int k0) {
    ra0 = *(const f32x4*)(a0f + k0);
    ra1 = *(const f32x4*)(a0f + k0 + 4);
  };
  auto WRITEA = [&](int buf) {
    u32x4 w;
    w[0] = cvt_pk_bf16(ra0[0], ra0[1]);
    w[1] = cvt_pk_bf16(ra0[2], ra0[3]);
    w[2] = cvt_pk_bf16(ra1[0], ra1[1]);
    w[3] = cvt_pk_bf16(ra1[2], ra1[3]);
    *(u32x4*)&As[buf][tid * 8] = w;
  };

  f32x4 acc[4] = {};
  const int NK = K / 32;
  LOADA(0);
  gload_lds16(b0, &Bs[0][wid * 512]);
  WRITEA(0);
  LOADA(32);
  asm volatile("s_waitcnt lgkmcnt(0)" ::: "memory");
#pragma unroll 1
  for (int ks = 0; ks < NK; ++ks) {
    if (ks + 1 < NK) {
      gload_lds16(b0 + (ks + 1) * 32, &Bs[(ks + 1) & 1][wid * 512]);
      asm volatile("s_waitcnt vmcnt(3)\n\ts_barrier" ::: "memory");
    } else {
      asm volatile("s_waitcnt vmcnt(0)\n\ts_barrier" ::: "memory");
    }
    __builtin_amdgcn_sched_barrier(0);

    const u16* Ab = &As[ks & 1][0];
    const u16* Bb = &Bs[ks & 1][0];
    const int lr = lane & 15, lk = (lane >> 4) * 8;
    bf16x8 af = *(const bf16x8*)&Ab[(wid * 16 + lr) * 32 + lk];
    __builtin_amdgcn_s_setprio(1);
#pragma unroll
    for (int n = 0; n < 4; ++n) {
      bf16x8 bfr = *(const bf16x8*)&Bb[(n * 16 + lr) * 32 + lk];
      acc[n] = MFMA16(af, bfr, acc[n]);
    }
    __builtin_amdgcn_s_setprio(0);

    if (ks + 1 < NK) {
      WRITEA((ks + 1) & 1);
      if (ks + 2 < NK) LOADA((ks + 2) * 32);
    }
    asm volatile("s_waitcnt lgkmcnt(0)\n\ts_barrier" ::: "memory");
  }

  const int lr = lane & 15, lg = lane >> 4;
#pragma unroll
  for (int n = 0; n < 4; ++n) {
    const int col = n * 16 + lr;
    const float bv = bias[col];
#pragma unroll
    for (int r = 0; r < 4; ++r) {
      const int row = brow + wid * 16 + lg * 4 + r;
      const float val = acc[n][r] + bv;
      if (sel)
        C1[((size_t)(row >> 11) * 64 + col) * 2048 + (row & 2047)] = f2bf(val);
      else
        C0[(size_t)row * 64 + col] = f2bf(val);
    }
  }
}

// ---------------- flash attention (MQA) v12: bf16 gload Q-phase + r12 attn core ----------------
// Grid (S/128, H, B): blocks sharing q-tile x have ids x+16h -> all on XCD x%8
// (q-tile L2-resident). Q-phase pure gload_lds from bf16 q (3 gloads/kstep,
// pre-swizzled source, linear dest; vmcnt(3) top, plain bottom barrier).
// Attn core = r12 (50.4us standalone). Measured r18: 58.8us total.
__global__ __launch_bounds__(512) void k_attn(const u16* __restrict__ qbf, const u16* __restrict__ WqT,
                                              const float* __restrict__ bq,
                                              const u16* __restrict__ Kh, const u16* __restrict__ VhT,
                                              u16* __restrict__ Out) {
  constexpr int S = 2048, D = 1024, NT = 32, K = 1024;
  __shared__ __align__(16) char smem[49152];
  const int tid = threadIdx.x, lane = tid & 63, wid = tid >> 6;
  const int lr = lane & 15, lg = lane >> 4;
  const int q0 = blockIdx.x * 128;
  const int h = blockIdx.y;
  const int b = blockIdx.z;

  const int r8 = lane >> 3, ssl = (lane & 7) ^ r8;  // pre-swizzled source chunk (row&7 == r8)

  // ---- Q-projection phase: AsQ [2][128][64] @0 (32KB), BsQ [2][64][64] @32K (16KB) ----
  u16* AsQ = (u16*)smem;
  u16* BsQ = (u16*)(smem + 32768);
  u16* Qlds = (u16*)(smem + 32768);         // [128][64] linear (post-loop, = Ps region)

  {
    const u16* qa = qbf + (size_t)(b * S + q0 + wid * 16 + r8) * K + ssl * 8;
    const u16* qb = WqT + (size_t)(h * 64 + wid * 8 + r8) * K + ssl * 8;

    auto STAGEQ = [&](int buf, int ks) {
      gload_lds16(qa + ks * 64, &AsQ[buf * 8192 + (wid * 16) * 64]);
      gload_lds16(qa + ks * 64 + (size_t)8 * K, &AsQ[buf * 8192 + (wid * 16 + 8) * 64]);
      gload_lds16(qb + ks * 64, &BsQ[buf * 4096 + (wid * 8) * 64]);
    };

    f32x4 accq[4] = {};
    STAGEQ(0, 0);
#pragma unroll 1
    for (int ks = 0; ks < 16; ++ks) {
      if (ks + 1 < 16) {
        STAGEQ((ks + 1) & 1, ks + 1);
        asm volatile("s_waitcnt vmcnt(3)\n\ts_barrier" ::: "memory");
      } else {
        asm volatile("s_waitcnt vmcnt(0)\n\ts_barrier" ::: "memory");
      }
      __builtin_amdgcn_sched_barrier(0);

      const char* Ab = (const char*)(AsQ + (ks & 1) * 8192);
      const char* Bb = (const char*)(BsQ + (ks & 1) * 4096);
      bf16x8 af[2];
#pragma unroll
      for (int kk = 0; kk < 2; ++kk) {
        const int row = wid * 16 + lr;
        af[kk] = *(const bf16x8*)(Ab + row * 128 + (((kk * 4 + lg) ^ (row & 7)) << 4));
      }
      __builtin_amdgcn_s_setprio(1);
#pragma unroll
      for (int kk = 0; kk < 2; ++kk)
#pragma unroll
        for (int n = 0; n < 4; ++n) {
          const int row = n * 16 + lr;
          bf16x8 bfr = *(const bf16x8*)(Bb + row * 128 + (((kk * 4 + lg) ^ (row & 7)) << 4));
          accq[n] = MFMA16(af[kk], bfr, accq[n]);
        }
      __builtin_amdgcn_s_setprio(0);
      asm volatile("s_barrier" ::: "memory");  // ring-2: reads of buf ks&1 done before overwrite
    }
    asm volatile("s_waitcnt lgkmcnt(0)\n\ts_barrier" ::: "memory");
    // Q-tile -> Qlds (linear [128][64], own wave rows), scale + bias folded
    const float qscale = 0.125f * 1.44269504089f;
#pragma unroll
    for (int n = 0; n < 4; ++n) {
      const float bv = bq[h * 64 + n * 16 + lr];
#pragma unroll
      for (int r = 0; r < 4; ++r)
        Qlds[(wid * 16 + lg * 4 + r) * 64 + n * 16 + lr] = f2bf((accq[n][r] + bv) * qscale);
    }
    asm volatile("s_waitcnt lgkmcnt(0)\n\ts_barrier" ::: "memory");
  }

  // ---- attention (r12 core) ----
  u16* Ks0 = (u16*)smem;                    // [2][64*64] = 16KB
  u16* Vs0 = (u16*)(smem + 16384);          // [2][64*64] = 16KB
  u16* Pw = Qlds + wid * (16 * 64);         // own slab of Ps region

  bf16x8 qf[2];
#pragma unroll
  for (int kk = 0; kk < 2; ++kk)
    qf[kk] = *(const bf16x8*)&Qlds[(wid * 16 + lr) * 64 + kk * 32 + lg * 8];

  const u16* ksrc = Kh + (size_t)(b * S + wid * 8 + r8) * 64 + ssl * 8;
  const u16* vsrc = VhT + (size_t)(b * 64 + wid * 8 + r8) * S + ssl * 8;

  float lsum = 0.f;
  f32x4 o[4] = {};
  const int pswz = (lr & 7) << 3;

  auto STAGE = [&](int buf, int t) {
    gload_lds16(ksrc + (size_t)(t * 64) * 64, &Ks0[buf * (64 * 64) + (wid * 8) * 64]);
    gload_lds16(vsrc + t * 64, &Vs0[buf * (64 * 64) + (wid * 8) * 64]);
  };

  STAGE(0, 0);
#pragma unroll 1
  for (int t = 0; t < NT; ++t) {
    if (t + 1 < NT) {
      STAGE((t + 1) & 1, t + 1);
      asm volatile("s_waitcnt vmcnt(2)\n\ts_barrier" ::: "memory");
    } else {
      asm volatile("s_waitcnt vmcnt(0)\n\ts_barrier" ::: "memory");
    }
    __builtin_amdgcn_sched_barrier(0);

    const u16* Kb = &Ks0[(t & 1) * (64 * 64)];
    const u16* Vb = &Vs0[(t & 1) * (64 * 64)];

    // QK^T swapped: z[ct][r] = S2[q = lr][kv = ct*16 + lg*4 + r]   (log2 domain)
    f32x4 z[4] = {};
    __builtin_amdgcn_s_setprio(1);
#pragma unroll
    for (int kk = 0; kk < 2; ++kk)
#pragma unroll
      for (int ct = 0; ct < 4; ++ct) {
        const int row = ct * 16 + lr;
        bf16x8 kf = *(const bf16x8*)&Kb[row * 64 + (((kk * 4 + lg) ^ (row & 7)) << 3)];
        z[ct] = MFMA16(kf, qf[kk], z[ct]);
      }
    __builtin_amdgcn_s_setprio(0);

    // P = exp2(z) (static max), pack to bf16, per-wave LDS (swizzled)
    float s = 0.f;
#pragma unroll
    for (int ct = 0; ct < 4; ++ct) {
      const float p0 = __builtin_amdgcn_exp2f(z[ct][0]);
      const float p1 = __builtin_amdgcn_exp2f(z[ct][1]);
      const float p2 = __builtin_amdgcn_exp2f(z[ct][2]);
      const float p3 = __builtin_amdgcn_exp2f(z[ct][3]);
      s += (p0 + p1) + (p2 + p3);
      uint2 pk;
      pk.x = cvt_pk_bf16(p0, p1);
      pk.y = cvt_pk_bf16(p2, p3);
      *(uint2*)&Pw[lr * 64 + ((ct * 16 + lg * 4) ^ pswz)] = pk;
    }
    lsum += s;

    // PV: o[nt][r] += P[q][kv] * V^T[d][kv],  q = lg*4+r, d = nt*16+lr
#pragma unroll
    for (int kk = 0; kk < 2; ++kk) {
      bf16x8 pa = *(const bf16x8*)&Pw[lr * 64 + ((kk * 32 + lg * 8) ^ pswz)];
      __builtin_amdgcn_s_setprio(1);
#pragma unroll
      for (int nt = 0; nt < 4; ++nt) {
        const int row = nt * 16 + lr;
        bf16x8 vf = *(const bf16x8*)&Vb[row * 64 + (((kk * 4 + lg) ^ (row & 7)) << 3)];
        o[nt] = MFMA16(pa, vf, o[nt]);
      }
      __builtin_amdgcn_s_setprio(0);
    }
    asm volatile("s_barrier" ::: "memory");
  }

  // epilogue: reduce per-lane l partials, divide, store
  lsum += __shfl_xor(lsum, 16);
  lsum += __shfl_xor(lsum, 32);
  const float linv = 1.f / lsum;
#pragma unroll
  for (int r = 0; r < 4; ++r) {
    const float li = __shfl(linv, (lane & 48) | (lg * 4 + r));
    const size_t row = (size_t)(b * S + q0 + wid * 16 + lg * 4 + r);
#pragma unroll
    for (int nt = 0; nt < 4; ++nt)
      Out[row * D + h * 64 + nt * 16 + lr] = f2bf(o[nt][r] * li);
  }
}

// ---------------- launcher ----------------
extern "C" void kernel_launch(void* const* d_in, const int* in_sizes, int n_in,
                              void* d_out, int out_size, void* d_ws, size_t ws_size,
                              hipStream_t stream) {
  const float* q  = (const float*)d_in[0];
  const float* k  = (const float*)d_in[1];
  const float* v  = (const float*)d_in[2];
  const float* Wq = (const float*)d_in[3];
  const float* bq = (const float*)d_in[4];
  const float* Wk = (const float*)d_in[5];
  const float* bk = (const float*)d_in[6];
  const float* Wv = (const float*)d_in[7];
  const float* bv = (const float*)d_in[8];
  const float* Wo = (const float*)d_in[9];
  const float* bo = (const float*)d_in[10];
  float* out = (float*)d_out;

  constexpr int B = 2, S = 2048, D = 1024, H = 16, HDc = 64;
  constexpr int M = B * S;  // 4096

  char* ws = (char*)d_ws;
  size_t off = 0;
  auto alloc = [&](size_t bytes) { char* p = ws + off; off += bytes; return p; };
  u16* WqT  = (u16*)alloc((size_t)D * D * 2);
  u16* WkvT = (u16*)alloc((size_t)2 * HDc * D * 2);
  u16* WoT  = (u16*)alloc((size_t)D * D * 2);
  u16* Kh   = (u16*)alloc((size_t)M * HDc * 2);
  u16* VhT  = (u16*)alloc((size_t)M * HDc * 2);
  u16* AO   = (u16*)alloc((size_t)M * D * 2);
  u16* q_bf = (u16*)alloc((size_t)M * D * 2);
  u16* WkT = WkvT;
  u16* WvT = WkvT + (size_t)HDc * D;

  // weight transposes (4 z-slices, no q-convert here)
  k_transpose4<<<dim3(32, 32, 4), dim3(32, 8), 0, stream>>>(Wq, WqT, Wo, WoT, Wk, WkT, Wv, WvT);
  // K + V projections (y=0,1) + q convert riding idle CUs (y=2..5)
  k_gemm64<<<dim3(M / 64, 6), 256, 0, stream>>>(k, v, WkT, WvT, bk, bv, Kh, VhT, D, q, q_bf);
  // attention with fused Q-projection (bf16 gload staging); grid (S/128, H, B)
  k_attn<<<dim3(S / 128, H, B), 512, 0, stream>>>(q_bf, WqT, bq, Kh, VhT, AO);
  // output projection (bf16 A via gload_lds, fp32 out + bias)
  k_gemm128<false, false><<<dim3((M / 128) * (D / 128)), 512, 0, stream>>>(AO, WoT, bo, out, M, D, D, 1.0f);
}

// Round 21
// 105.885 us; speedup vs baseline: 1.0506x; 1.0245x over previous
//
#include <hip/hip_runtime.h>
#include <cstdint>
#include <cstddef>

typedef unsigned short u16;
typedef uint32_t u32;
typedef __bf16 bf16x8 __attribute__((ext_vector_type(8)));
typedef float  f32x4  __attribute__((ext_vector_type(4)));
typedef u16    u16x4  __attribute__((ext_vector_type(4)));
typedef u32    u32x4  __attribute__((ext_vector_type(4)));

#define DEV static __device__ __forceinline__
#define MFMA16(a, b, c) __builtin_amdgcn_mfma_f32_16x16x32_bf16(a, b, c, 0, 0, 0)

DEV u16 f2bf(float x) {
  unsigned u = __float_as_uint(x);
  u += 0x7fffu + ((u >> 16) & 1u);
  return (u16)(u >> 16);
}

DEV u32 cvt_pk_bf16(float lo, float hi) {  // [15:0]=bf16(lo), [31:16]=bf16(hi), RNE
  u32 r;
  asm("v_cvt_pk_bf16_f32 %0, %1, %2" : "=v"(r) : "v"(lo), "v"(hi));
  return r;
}

DEV void gload_lds16(const void* g, void* l) {
  __builtin_amdgcn_global_load_lds(
      (__attribute__((address_space(1))) void*)(void*)g,
      (__attribute__((address_space(3))) void*)l, 16, 0, 0);
}

// ---------------- all 4 weight transposes in ONE dispatch ----------------
__global__ void k_transpose4(const float* __restrict__ Wq, u16* __restrict__ WqT,
                             const float* __restrict__ Wo, u16* __restrict__ WoT,
                             const float* __restrict__ Wk, u16* __restrict__ WkT,
                             const float* __restrict__ Wv, u16* __restrict__ WvT) {
  __shared__ float tile[32][33];
  const int z = blockIdx.z;
  const int C = z < 2 ? 1024 : 64;
  constexpr int R = 1024;
  if (blockIdx.x * 32 >= C) return;
  const float* in = z == 0 ? Wq : z == 1 ? Wo : z == 2 ? Wk : Wv;
  u16* out = z == 0 ? WqT : z == 1 ? WoT : z == 2 ? WkT : WvT;
  int bx = blockIdx.x * 32, by = blockIdx.y * 32;
  int tx = threadIdx.x, ty = threadIdx.y;
#pragma unroll
  for (int j = 0; j < 4; ++j)
    tile[ty + j * 8][tx] = in[(size_t)(by + ty + j * 8) * C + bx + tx];
  __syncthreads();
#pragma unroll
  for (int j = 0; j < 4; ++j)
    out[(size_t)(bx + ty + j * 8) * R + by + tx] = f2bf(tile[tx][ty + j * 8]);
}

// ---------------- 128x128 tile NT GEMM v4: ring-4 depth-2, 8 waves, XCD swizzle ----------------
// bf16 A via gload_lds (O-projection). Ring-4 single-barrier discipline (r6-proven):
// writer buf (ks+2)&3 vs readers (ks-1)&3 / ks&3 — distinct mod 4 at <1-iter skew.
// Tiles are 128x32 u16 = 8KB each -> As[4]+Bs[4] = 64KB (fits; 1 block/CU anyway).
// STAGE = 2 gloads; steady vmcnt(4) = tiles ks+1,ks+2 in flight; tail 2 -> 0.
template <bool OUT_BF16>
__global__ __launch_bounds__(512) void k_gemm128(const u16* __restrict__ A, const u16* __restrict__ Bt,
                                                 const float* __restrict__ bias, void* __restrict__ Cout,
                                                 int M, int N, int K, float scale) {
  __shared__ u16 As[4][128 * 32];
  __shared__ u16 Bs[4][128 * 32];
  const int tid = threadIdx.x, lane = tid & 63, wid = tid >> 6;  // wid 0..7
  const int s = blockIdx.x;
  const int xr = s & 7, t = s >> 3;
  const int bx = t & 7;
  const int by = (t >> 3) * 8 + xr;   // by % 8 == XCD id
  const int brow = by * 128, bcol = bx * 128;
  const int wr = (wid >> 2) * 64, wc = (wid & 3) * 32;

  const int e0 = wid * 512 + lane * 8;
  const u16* b0 = Bt + (size_t)(bcol + (e0 >> 5)) * K + (e0 & 31);
  const u16* a0 = A + (size_t)(brow + (e0 >> 5)) * K + (e0 & 31);

  auto STAGE = [&](int buf, int k0) {
    gload_lds16(a0 + k0, &As[buf][wid * 512]);
    gload_lds16(b0 + k0, &Bs[buf][wid * 512]);
  };

  f32x4 acc[4][2] = {};
  const int NK = K / 32;
  STAGE(0, 0);
  STAGE(1, 32);
#pragma unroll 1
  for (int ks = 0; ks < NK; ++ks) {
    if (ks + 2 < NK) {
      STAGE((ks + 2) & 3, (ks + 2) * 32);  // depth-2: two tiles stay in flight
      asm volatile("s_waitcnt vmcnt(4)\n\ts_barrier" ::: "memory");
    } else if (ks + 1 < NK) {
      asm volatile("s_waitcnt vmcnt(2)\n\ts_barrier" ::: "memory");
    } else {
      asm volatile("s_waitcnt vmcnt(0)\n\ts_barrier" ::: "memory");
    }
    __builtin_amdgcn_sched_barrier(0);

    const u16* Ab = &As[ks & 3][0];
    const u16* Bb = &Bs[ks & 3][0];
    const int lr = lane & 15, lk = (lane >> 4) * 8;
    bf16x8 af[4], bfr[2];
#pragma unroll
    for (int m = 0; m < 4; ++m) af[m] = *(const bf16x8*)&Ab[(wr + m * 16 + lr) * 32 + lk];
#pragma unroll
    for (int n = 0; n < 2; ++n) bfr[n] = *(const bf16x8*)&Bb[(wc + n * 16 + lr) * 32 + lk];
    __builtin_amdgcn_s_setprio(1);
#pragma unroll
    for (int m = 0; m < 4; ++m)
#pragma unroll
      for (int n = 0; n < 2; ++n) acc[m][n] = MFMA16(af[m], bfr[n], acc[m][n]);
    __builtin_amdgcn_s_setprio(0);
  }

  const int lr = lane & 15, lg = lane >> 4;
#pragma unroll
  for (int m = 0; m < 4; ++m)
#pragma unroll
    for (int n = 0; n < 2; ++n) {
      const int col = bcol + wc + n * 16 + lr;
      const float bv = bias ? bias[col] : 0.f;
#pragma unroll
      for (int r = 0; r < 4; ++r) {
        const int row = brow + wr + m * 16 + lg * 4 + r;
        float val = (acc[m][n][r] + bv) * scale;
        if constexpr (OUT_BF16) ((u16*)Cout)[(size_t)row * N + col] = f2bf(val);
        else ((float*)Cout)[(size_t)row * N + col] = val;
      }
    }
}

// ---------------- fused K+V projections + q-convert rideshare (r19 verified) ----------------
__global__ __launch_bounds__(256) void k_gemm64(const float* __restrict__ A0, const float* __restrict__ A1,
                                                const u16* __restrict__ Bt0, const u16* __restrict__ Bt1,
                                                const float* __restrict__ bias0, const float* __restrict__ bias1,
                                                u16* __restrict__ C0, u16* __restrict__ C1, int K,
                                                const float* __restrict__ qsrc, u16* __restrict__ qbf) {
  const int sel = blockIdx.y;
  if (sel >= 2) {  // q convert: slice (sel-2) of 4, 64 blocks each; 4096 f32x4/block
    const f32x4* src = (const f32x4*)qsrc;
    u16x4* dst = (u16x4*)qbf;
    const int base = ((sel - 2) * 64 + blockIdx.x) * 4096 + threadIdx.x;
#pragma unroll 4
    for (int i = 0; i < 16; ++i) {
      f32x4 f = src[base + i * 256];
      u16x4 o;
      o[0] = f2bf(f[0]); o[1] = f2bf(f[1]); o[2] = f2bf(f[2]); o[3] = f2bf(f[3]);
      dst[base + i * 256] = o;
    }
    return;
  }
  __shared__ u16 As[2][64 * 32];
  __shared__ u16 Bs[2][64 * 32];
  const float* Af = sel ? A1 : A0;
  const u16* Bt = sel ? Bt1 : Bt0;
  const float* bias = sel ? bias1 : bias0;
  const int tid = threadIdx.x, lane = tid & 63, wid = tid >> 6;  // 4 waves
  const int brow = blockIdx.x * 64;
  const int e0 = wid * 512 + lane * 8;
  const u16* b0 = Bt + (size_t)(e0 >> 5) * K + (e0 & 31);
  const float* a0f = Af + (size_t)(brow + (tid >> 2)) * K + (tid & 3) * 8;

  f32x4 ra0, ra1;
  auto LOADA = [&](int k0) {
    ra0 = *(const f32x4*)(a0f + k0);
    ra1 = *(const f32x4*)(a0f + k0 + 4);
  };
  auto WRITEA = [&](int buf) {
    u32x4 w;
    w[0] = cvt_pk_bf16(ra0[0], ra0[1]);
    w[1] = cvt_pk_bf16(ra0[2], ra0[3]);
    w[2] = cvt_pk_bf16(ra1[0], ra1[1]);
    w[3] = cvt_pk_bf16(ra1[2], ra1[3]);
    *(u32x4*)&As[buf][tid * 8] = w;
  };

  f32x4 acc[4] = {};
  const int NK = K / 32;
  LOADA(0);
  gload_lds16(b0, &Bs[0][wid * 512]);
  WRITEA(0);
  LOADA(32);
  asm volatile("s_waitcnt lgkmcnt(0)" ::: "memory");
#pragma unroll 1
  for (int ks = 0; ks < NK; ++ks) {
    if (ks + 1 < NK) {
      gload_lds16(b0 + (ks + 1) * 32, &Bs[(ks + 1) & 1][wid * 512]);
      asm volatile("s_waitcnt vmcnt(3)\n\ts_barrier" ::: "memory");
    } else {
      asm volatile("s_waitcnt vmcnt(0)\n\ts_barrier" ::: "memory");
    }
    __builtin_amdgcn_sched_barrier(0);

    const u16* Ab = &As[ks & 1][0];
    const u16* Bb = &Bs[ks & 1][0];
    const int lr = lane & 15, lk = (lane >> 4) * 8;
    bf16x8 af = *(const bf16x8*)&Ab[(wid * 16 + lr) * 32 + lk];
    __builtin_amdgcn_s_setprio(1);
#pragma unroll
    for (int n = 0; n < 4; ++n) {
      bf16x8 bfr = *(const bf16x8*)&Bb[(n * 16 + lr) * 32 + lk];
      acc[n] = MFMA16(af, bfr, acc[n]);
    }
    __builtin_amdgcn_s_setprio(0);

    if (ks + 1 < NK) {
      WRITEA((ks + 1) & 1);
      if (ks + 2 < NK) LOADA((ks + 2) * 32);
    }
    asm volatile("s_waitcnt lgkmcnt(0)\n\ts_barrier" ::: "memory");
  }

  const int lr = lane & 15, lg = lane >> 4;
#pragma unroll
  for (int n = 0; n < 4; ++n) {
    const int col = n * 16 + lr;
    const float bv = bias[col];
#pragma unroll
    for (int r = 0; r < 4; ++r) {
      const int row = brow + wid * 16 + lg * 4 + r;
      const float val = acc[n][r] + bv;
      if (sel)
        C1[((size_t)(row >> 11) * 64 + col) * 2048 + (row & 2047)] = f2bf(val);
      else
        C0[(size_t)row * 64 + col] = f2bf(val);
    }
  }
}

// ---------------- flash attention (MQA) v12 (r19 verified, 58.8us): ring-2 Q-phase ----------------
// Grid (S/128, H, B): blocks sharing q-tile x all land on XCD x%8 (q L2-resident).
// Q-phase: ring-2 (A tile 16KB x2 + B tile 8KB x2 = 48KB — ring-4 does NOT fit,
// r20's overlap bug). 3 gloads/kstep, pre-swizzled source, linear dest; vmcnt(3)
// top wait, plain fenced bottom barrier. Attn core = r12 ring-2.
__global__ __launch_bounds__(512) void k_attn(const u16* __restrict__ qbf, const u16* __restrict__ WqT,
                                              const float* __restrict__ bq,
                                              const u16* __restrict__ Kh, const u16* __restrict__ VhT,
                                              u16* __restrict__ Out) {
  constexpr int S = 2048, D = 1024, NT = 32, K = 1024;
  __shared__ __align__(16) char smem[49152];
  const int tid = threadIdx.x, lane = tid & 63, wid = tid >> 6;
  const int lr = lane & 15, lg = lane >> 4;
  const int q0 = blockIdx.x * 128;
  const int h = blockIdx.y;
  const int b = blockIdx.z;

  const int r8 = lane >> 3, ssl = (lane & 7) ^ r8;  // pre-swizzled source chunk (row&7 == r8)

  // ---- Q-projection phase: AsQ [2][128][64] @0 (32KB), BsQ [2][64][64] @32K (16KB) ----
  u16* AsQ = (u16*)smem;
  u16* BsQ = (u16*)(smem + 32768);
  u16* Qlds = (u16*)(smem + 32768);         // [128][64] linear (post-loop, = Ps region)

  {
    const u16* qa = qbf + (size_t)(b * S + q0 + wid * 16 + r8) * K + ssl * 8;
    const u16* qb = WqT + (size_t)(h * 64 + wid * 8 + r8) * K + ssl * 8;

    auto STAGEQ = [&](int buf, int ks) {
      gload_lds16(qa + ks * 64, &AsQ[buf * 8192 + (wid * 16) * 64]);
      gload_lds16(qa + ks * 64 + (size_t)8 * K, &AsQ[buf * 8192 + (wid * 16 + 8) * 64]);
      gload_lds16(qb + ks * 64, &BsQ[buf * 4096 + (wid * 8) * 64]);
    };

    f32x4 accq[4] = {};
    STAGEQ(0, 0);
#pragma unroll 1
    for (int ks = 0; ks < 16; ++ks) {
      if (ks + 1 < 16) {
        STAGEQ((ks + 1) & 1, ks + 1);
        asm volatile("s_waitcnt vmcnt(3)\n\ts_barrier" ::: "memory");
      } else {
        asm volatile("s_waitcnt vmcnt(0)\n\ts_barrier" ::: "memory");
      }
      __builtin_amdgcn_sched_barrier(0);

      const char* Ab = (const char*)(AsQ + (ks & 1) * 8192);
      const char* Bb = (const char*)(BsQ + (ks & 1) * 4096);
      bf16x8 af[2];
#pragma unroll
      for (int kk = 0; kk < 2; ++kk) {
        const int row = wid * 16 + lr;
        af[kk] = *(const bf16x8*)(Ab + row * 128 + (((kk * 4 + lg) ^ (row & 7)) << 4));
      }
      __builtin_amdgcn_s_setprio(1);
#pragma unroll
      for (int kk = 0; kk < 2; ++kk)
#pragma unroll
        for (int n = 0; n < 4; ++n) {
          const int row = n * 16 + lr;
          bf16x8 bfr = *(const bf16x8*)(Bb + row * 128 + (((kk * 4 + lg) ^ (row & 7)) << 4));
          accq[n] = MFMA16(af[kk], bfr, accq[n]);
        }
      __builtin_amdgcn_s_setprio(0);
      asm volatile("s_barrier" ::: "memory");  // ring-2: reads of buf ks&1 done before overwrite
    }
    asm volatile("s_waitcnt lgkmcnt(0)\n\ts_barrier" ::: "memory");
    // Q-tile -> Qlds (linear [128][64], own wave rows), scale + bias folded
    const float qscale = 0.125f * 1.44269504089f;
#pragma unroll
    for (int n = 0; n < 4; ++n) {
      const float bv = bq[h * 64 + n * 16 + lr];
#pragma unroll
      for (int r = 0; r < 4; ++r)
        Qlds[(wid * 16 + lg * 4 + r) * 64 + n * 16 + lr] = f2bf((accq[n][r] + bv) * qscale);
    }
    asm volatile("s_waitcnt lgkmcnt(0)\n\ts_barrier" ::: "memory");
  }

  // ---- attention (r12 core) ----
  u16* Ks0 = (u16*)smem;                    // [2][64*64] = 16KB
  u16* Vs0 = (u16*)(smem + 16384);          // [2][64*64] = 16KB
  u16* Pw = Qlds + wid * (16 * 64);         // own slab of Ps region

  bf16x8 qf[2];
#pragma unroll
  for (int kk = 0; kk < 2; ++kk)
    qf[kk] = *(const bf16x8*)&Qlds[(wid * 16 + lr) * 64 + kk * 32 + lg * 8];

  const u16* ksrc = Kh + (size_t)(b * S + wid * 8 + r8) * 64 + ssl * 8;
  const u16* vsrc = VhT + (size_t)(b * 64 + wid * 8 + r8) * S + ssl * 8;

  float lsum = 0.f;
  f32x4 o[4] = {};
  const int pswz = (lr & 7) << 3;

  auto STAGE = [&](int buf, int t) {
    gload_lds16(ksrc + (size_t)(t * 64) * 64, &Ks0[buf * (64 * 64) + (wid * 8) * 64]);
    gload_lds16(vsrc + t * 64, &Vs0[buf * (64 * 64) + (wid * 8) * 64]);
  };

  STAGE(0, 0);
#pragma unroll 1
  for (int t = 0; t < NT; ++t) {
    if (t + 1 < NT) {
      STAGE((t + 1) & 1, t + 1);
      asm volatile("s_waitcnt vmcnt(2)\n\ts_barrier" ::: "memory");
    } else {
      asm volatile("s_waitcnt vmcnt(0)\n\ts_barrier" ::: "memory");
    }
    __builtin_amdgcn_sched_barrier(0);

    const u16* Kb = &Ks0[(t & 1) * (64 * 64)];
    const u16* Vb = &Vs0[(t & 1) * (64 * 64)];

    // QK^T swapped: z[ct][r] = S2[q = lr][kv = ct*16 + lg*4 + r]   (log2 domain)
    f32x4 z[4] = {};
    __builtin_amdgcn_s_setprio(1);
#pragma unroll
    for (int kk = 0; kk < 2; ++kk)
#pragma unroll
      for (int ct = 0; ct < 4; ++ct) {
        const int row = ct * 16 + lr;
        bf16x8 kf = *(const bf16x8*)&Kb[row * 64 + (((kk * 4 + lg) ^ (row & 7)) << 3)];
        z[ct] = MFMA16(kf, qf[kk], z[ct]);
      }
    __builtin_amdgcn_s_setprio(0);

    // P = exp2(z) (static max), pack to bf16, per-wave LDS (swizzled)
    float s = 0.f;
#pragma unroll
    for (int ct = 0; ct < 4; ++ct) {
      const float p0 = __builtin_amdgcn_exp2f(z[ct][0]);
      const float p1 = __builtin_amdgcn_exp2f(z[ct][1]);
      const float p2 = __builtin_amdgcn_exp2f(z[ct][2]);
      const float p3 = __builtin_amdgcn_exp2f(z[ct][3]);
      s += (p0 + p1) + (p2 + p3);
      uint2 pk;
      pk.x = cvt_pk_bf16(p0, p1);
      pk.y = cvt_pk_bf16(p2, p3);
      *(uint2*)&Pw[lr * 64 + ((ct * 16 + lg * 4) ^ pswz)] = pk;
    }
    lsum += s;

    // PV: o[nt][r] += P[q][kv] * V^T[d][kv],  q = lg*4+r, d = nt*16+lr
#pragma unroll
    for (int kk = 0; kk < 2; ++kk) {
      bf16x8 pa = *(const bf16x8*)&Pw[lr * 64 + ((kk * 32 + lg * 8) ^ pswz)];
      __builtin_amdgcn_s_setprio(1);
#pragma unroll
      for (int nt = 0; nt < 4; ++nt) {
        const int row = nt * 16 + lr;
        bf16x8 vf = *(const bf16x8*)&Vb[row * 64 + (((kk * 4 + lg) ^ (row & 7)) << 3)];
        o[nt] = MFMA16(pa, vf, o[nt]);
      }
      __builtin_amdgcn_s_setprio(0);
    }
    asm volatile("s_barrier" ::: "memory");
  }

  // epilogue: reduce per-lane l partials, divide, store
  lsum += __shfl_xor(lsum, 16);
  lsum += __shfl_xor(lsum, 32);
  const float linv = 1.f / lsum;
#pragma unroll
  for (int r = 0; r < 4; ++r) {
    const float li = __shfl(linv, (lane & 48) | (lg * 4 + r));
    const size_t row = (size_t)(b * S + q0 + wid * 16 + lg * 4 + r);
#pragma unroll
    for (int nt = 0; nt < 4; ++nt)
      Out[row * D + h * 64 + nt * 16 + lr] = f2bf(o[nt][r] * li);
  }
}

// ---------------- launcher ----------------
extern "C" void kernel_launch(void* const* d_in, const int* in_sizes, int n_in,
                              void* d_out, int out_size, void* d_ws, size_t ws_size,
                              hipStream_t stream) {
  const float* q  = (const float*)d_in[0];
  const float* k  = (const float*)d_in[1];
  const float* v  = (const float*)d_in[2];
  const float* Wq = (const float*)d_in[3];
  const float* bq = (const float*)d_in[4];
  const float* Wk = (const float*)d_in[5];
  const float* bk = (const float*)d_in[6];
  const float* Wv = (const float*)d_in[7];
  const float* bv = (const float*)d_in[8];
  const float* Wo = (const float*)d_in[9];
  const float* bo = (const float*)d_in[10];
  float* out = (float*)d_out;

  constexpr int B = 2, S = 2048, D = 1024, H = 16, HDc = 64;
  constexpr int M = B * S;  // 4096

  char* ws = (char*)d_ws;
  size_t off = 0;
  auto alloc = [&](size_t bytes) { char* p = ws + off; off += bytes; return p; };
  u16* WqT  = (u16*)alloc((size_t)D * D * 2);
  u16* WkvT = (u16*)alloc((size_t)2 * HDc * D * 2);
  u16* WoT  = (u16*)alloc((size_t)D * D * 2);
  u16* Kh   = (u16*)alloc((size_t)M * HDc * 2);
  u16* VhT  = (u16*)alloc((size_t)M * HDc * 2);
  u16* AO   = (u16*)alloc((size_t)M * D * 2);
  u16* q_bf = (u16*)alloc((size_t)M * D * 2);
  u16* WkT = WkvT;
  u16* WvT = WkvT + (size_t)HDc * D;

  // weight transposes
  k_transpose4<<<dim3(32, 32, 4), dim3(32, 8), 0, stream>>>(Wq, WqT, Wo, WoT, Wk, WkT, Wv, WvT);
  // K + V projections (y=0,1) + q convert riding idle CUs (y=2..5)
  k_gemm64<<<dim3(M / 64, 6), 256, 0, stream>>>(k, v, WkT, WvT, bk, bv, Kh, VhT, D, q, q_bf);
  // attention with fused Q-projection (ring-2 Q-phase, r19-verified); grid (S/128, H, B)
  k_attn<<<dim3(S / 128, H, B), 512, 0, stream>>>(q_bf, WqT, bq, Kh, VhT, AO);
  // output projection (ring-4 depth-2, fp32 out + bias)
  k_gemm128<false><<<dim3((M / 128) * (D / 128)), 512, 0, stream>>>(AO, WoT, bo, out, M, D, D, 1.0f);
}